// Round 10
// baseline (448.142 us; speedup 1.0000x reference)
//
#include <hip/hip_runtime.h>

#define M_NODES 100000
#define N_EDGES 3200000
#define D 128
#define NBUCK 1563            // ceil(100000 / 64) buckets of 64 rows (gather tiles)
#define FILL_CHUNK 12288      // edges per fill block (512 thr * 6 * 4)
#define FILL_BLOCKS 261       // ceil(3.2M / 12288)
#define GEMM_BLOCKS 1563      // ceil(100000 / 64) row tiles of 64 (MFMA)
#define PREP_BLOCKS (FILL_BLOCKS + GEMM_BLOCKS)
#define BUCK_CAP 4096         // fixed slots per bucket (mean 2048, sigma ~45)
#define NSEG 7                // col segments of 16384 (100000 -> segs 0..6)

// ---------------- workspace layout (bytes) ----------------
#define OFF_SUP16  0ull            // 100000*64 u32 (paired bf16) = 25,600,000
#define OFF_BCNT   25600000ull     // 1563 int (+pad to 8192)
#define OFF_REC    25608192ull     // 1563*4096 int2 = 51,216,384 (fixed slots)
#define WS_NEEDED  76824576ull

typedef __attribute__((ext_vector_type(8))) short short8;
typedef __attribute__((ext_vector_type(4))) float f32x4;

__device__ __forceinline__ unsigned short f2bf(float f) {
    unsigned u = __float_as_uint(f);
    u += 0x7fff + ((u >> 16) & 1);      // round-to-nearest-even
    return (unsigned short)(u >> 16);
}
__device__ __forceinline__ float bf2f(unsigned short h) {
    return __uint_as_float((unsigned)h << 16);
}
// word k of a row holds features (2k, 2k+1)
__device__ __forceinline__ float2 bfpair(unsigned u) {
    float2 r;
    r.x = __uint_as_float(u << 16);
    r.y = __uint_as_float(u & 0xffff0000u);
    return r;
}

// ---------------- fused prep: edge fill (memory-bound) + MFMA GEMM -----------
// (unchanged from round 9 — verified, prep < 113 us)
__global__ __launch_bounds__(512) void prep_kernel(const float* __restrict__ x,
                                                   const float* __restrict__ w,
                                                   unsigned* __restrict__ sup16,
                                                   const int* __restrict__ rows,
                                                   const int* __restrict__ cols,
                                                   const float* __restrict__ vals,
                                                   int* __restrict__ bcnt,
                                                   int2* __restrict__ rec,
                                                   int M) {
    __shared__ __align__(16) char smem[37120];
    const int tid = threadIdx.x;

    if (blockIdx.x < FILL_BLOCKS) {
        // ---- fill path: block-batched bucket sort into fixed slots ----
        int* cnt = (int*)smem;                            // 6252 B
        int* bas = (int*)(smem + 6256);                   // 6252 B
        unsigned short* lrank = (unsigned short*)(smem + 12512); // 24576 B
        for (int i = tid; i < NBUCK; i += 512) cnt[i] = 0;
        __syncthreads();
        const long long base = (long long)blockIdx.x * FILL_CHUNK;

        // phase 1: per-edge rank within (block, bucket)
#pragma unroll
        for (int i = 0; i < 6; ++i) {
            const int li = (i * 512 + tid) * 4;
            const long long e = base + li;
            if (e < N_EDGES) {
                const int4 r = *(const int4*)&rows[e];
                lrank[li + 0] = (unsigned short)atomicAdd(&cnt[r.x >> 6], 1);
                lrank[li + 1] = (unsigned short)atomicAdd(&cnt[r.y >> 6], 1);
                lrank[li + 2] = (unsigned short)atomicAdd(&cnt[r.z >> 6], 1);
                lrank[li + 3] = (unsigned short)atomicAdd(&cnt[r.w >> 6], 1);
            }
        }
        __syncthreads();
        // phase 2: reserve a run in the bucket's fixed slot range
        for (int i = tid; i < NBUCK; i += 512)
            bas[i] = cnt[i] ? atomicAdd(&bcnt[i], cnt[i]) : 0;
        __syncthreads();
        // phase 3: scatter records (drop beyond cap; >40 sigma, never in practice)
#pragma unroll
        for (int i = 0; i < 6; ++i) {
            const int li = (i * 512 + tid) * 4;
            const long long e = base + li;
            if (e < N_EDGES) {
                const int4   r = *(const int4*)&rows[e];
                const int4   c = *(const int4*)&cols[e];
                const float4 v = *(const float4*)&vals[e];
                int p;
                p = bas[r.x >> 6] + lrank[li + 0];
                if (p < BUCK_CAP)
                    rec[(size_t)(r.x >> 6) * BUCK_CAP + p] =
                        make_int2(c.x | ((r.x & 63) << 20), __float_as_int(v.x));
                p = bas[r.y >> 6] + lrank[li + 1];
                if (p < BUCK_CAP)
                    rec[(size_t)(r.y >> 6) * BUCK_CAP + p] =
                        make_int2(c.y | ((r.y & 63) << 20), __float_as_int(v.y));
                p = bas[r.z >> 6] + lrank[li + 2];
                if (p < BUCK_CAP)
                    rec[(size_t)(r.z >> 6) * BUCK_CAP + p] =
                        make_int2(c.z | ((r.z & 63) << 20), __float_as_int(v.z));
                p = bas[r.w >> 6] + lrank[li + 3];
                if (p < BUCK_CAP)
                    rec[(size_t)(r.w >> 6) * BUCK_CAP + p] =
                        make_int2(c.w | ((r.w & 63) << 20), __float_as_int(v.w));
            }
        }
        return;
    }

    // ---- GEMM path: MFMA, 64-row tile, 8 waves -------------------------------
    short* xh = (short*)smem;               // [64][40]  x_hi   (5120 B)
    short* xl = (short*)(smem + 5120);      // [64][40]  x_lo   (5120 B)
    short* wh = (short*)(smem + 10240);     // [128][40] W_hi^T (10240 B)
    short* wl = (short*)(smem + 20480);     // [128][40] W_lo^T (10240 B)

    const int r0   = (blockIdx.x - FILL_BLOCKS) * 64;
    const int wv   = tid >> 6;        // wave 0..7
    const int lane = tid & 63;
    const int g    = lane >> 4;       // k-group 0..3
    const int ml   = lane & 15;

    const int mt = wv & 3;            // m-tile (rows mt*16..+15)
    const int ng = (wv >> 2) * 4;     // first n-tile (cols ng*16..)

    f32x4 acc[4];
#pragma unroll
    for (int i = 0; i < 4; ++i) acc[i] = (f32x4){0.f, 0.f, 0.f, 0.f};

    for (int c0 = 0; c0 < 128; c0 += 32) {
        // stage x chunk: 64 rows x 32 k -> hi/lo bf16
        {
            const int r  = tid >> 3;           // 0..63
            const int k0 = (tid & 7) * 4;      // 0..28
            float4 v = make_float4(0.f, 0.f, 0.f, 0.f);
            if (r0 + r < M)
                v = *(const float4*)&x[(size_t)(r0 + r) * D + c0 + k0];
            unsigned short h0 = f2bf(v.x), h1 = f2bf(v.y),
                           h2 = f2bf(v.z), h3 = f2bf(v.w);
            unsigned short l0 = f2bf(v.x - bf2f(h0)), l1 = f2bf(v.y - bf2f(h1)),
                           l2 = f2bf(v.z - bf2f(h2)), l3 = f2bf(v.w - bf2f(h3));
            uint2 ph, pl;
            ph.x = (unsigned)h0 | ((unsigned)h1 << 16);
            ph.y = (unsigned)h2 | ((unsigned)h3 << 16);
            pl.x = (unsigned)l0 | ((unsigned)l1 << 16);
            pl.y = (unsigned)l2 | ((unsigned)l3 << 16);
            *(uint2*)&xh[r * 40 + k0] = ph;
            *(uint2*)&xl[r * 40 + k0] = pl;
        }
        // stage W chunk transposed: 32 k x 128 col -> hi/lo bf16 at [col][k]
        {
            const int k    = tid >> 4;         // 0..31
            const int col0 = (tid & 15) * 8;   // 0..120
            const float4 a = *(const float4*)&w[(size_t)(c0 + k) * D + col0];
            const float4 bq = *(const float4*)&w[(size_t)(c0 + k) * D + col0 + 4];
            const float vv[8] = {a.x, a.y, a.z, a.w, bq.x, bq.y, bq.z, bq.w};
#pragma unroll
            for (int j = 0; j < 8; ++j) {
                const unsigned short h = f2bf(vv[j]);
                wh[(col0 + j) * 40 + k] = (short)h;
                wl[(col0 + j) * 40 + k] = (short)f2bf(vv[j] - bf2f(h));
            }
        }
        __syncthreads();

        const short8 a_hi = *(const short8*)&xh[(mt * 16 + ml) * 40 + g * 8];
        const short8 a_lo = *(const short8*)&xl[(mt * 16 + ml) * 40 + g * 8];
#pragma unroll
        for (int i = 0; i < 4; ++i) {
            const int col = (ng + i) * 16 + ml;
            const short8 b_hi = *(const short8*)&wh[col * 40 + g * 8];
            const short8 b_lo = *(const short8*)&wl[col * 40 + g * 8];
            acc[i] = __builtin_amdgcn_mfma_f32_16x16x32_bf16(a_hi, b_hi, acc[i], 0, 0, 0);
            acc[i] = __builtin_amdgcn_mfma_f32_16x16x32_bf16(a_lo, b_hi, acc[i], 0, 0, 0);
            acc[i] = __builtin_amdgcn_mfma_f32_16x16x32_bf16(a_hi, b_lo, acc[i], 0, 0, 0);
        }
        __syncthreads();
    }

    // epilogue: pair adjacent cols via shfl_xor(1) -> one u32 word (2k,2k+1)
#pragma unroll
    for (int i = 0; i < 4; ++i) {
#pragma unroll
        for (int reg = 0; reg < 4; ++reg) {
            const float mine  = acc[i][reg];
            const float other = __shfl_xor(mine, 1);
            if (!(lane & 1)) {
                const unsigned uo = (unsigned)f2bf(mine) | ((unsigned)f2bf(other) << 16);
                const int grow = r0 + mt * 16 + g * 4 + reg;
                if (grow < M) {
                    const int word = (wv >> 2) * 32 + i * 8 + (ml >> 1);
                    sup16[(size_t)grow * 64 + word] = uo;
                }
            }
        }
    }
}

// ---------------- gather-reduce: (seg,row) sort + 8-deep col-swept gather ----
// One 512-thread block per bucket. Phase A: counting-sort by key =
// (col>>14)*64 + rowlo (512 keys); elist keeps rowlo in bits 20-25. Phase B:
// per segment, wave w's 8 rows form ONE contiguous elist range -> unguarded
// 8-deep load batches (r6-level MLP); per-edge accumulation dispatches via a
// WAVE-UNIFORM readfirstlane switch (scalar s_cbranch, co-issues with VALU).
// Goal: r7's fabric traffic (~212MB) at r6's bandwidth (~3.6 TB/s).
__global__ __launch_bounds__(512) void gather_kernel(const unsigned* __restrict__ sup16,
                                                     const int* __restrict__ bcnt,
                                                     const int2* __restrict__ rec,
                                                     const float* __restrict__ norm,
                                                     const float* __restrict__ bias,
                                                     float* __restrict__ out) {
    __shared__ int2 elist[BUCK_CAP];              // 32 KB (seg,row)-sorted edges
    __shared__ int cnt[512];                      // counts -> scatter cursors
    __shared__ int rbase[514];                    // run starts (key-ordered)
    const int tid = threadIdx.x;
    const int b   = blockIdx.x;

    cnt[tid] = 0;
    __syncthreads();
    const int n = min(bcnt[b], BUCK_CAP);
    const int2* __restrict__ recb = rec + (size_t)b * BUCK_CAP;

    // phase A1: count per (seg, row)
    for (int k = tid; k < n; k += 512) {
        const int ex = recb[k].x;
        const int key = (((ex & 0xFFFFF) >> 14) << 6) | ((ex >> 20) & 63);
        atomicAdd(&cnt[key], 1);
    }
    __syncthreads();
    // phase A2: exclusive scan of 512 counts (tsum aliased onto elist)
    int* tsum = (int*)elist;
    const int myc = cnt[tid];
    tsum[tid] = myc;
    __syncthreads();
    for (int off = 1; off < 512; off <<= 1) {
        const int v = (tid >= off) ? tsum[tid - off] : 0;
        __syncthreads();
        tsum[tid] += v;
        __syncthreads();
    }
    const int excl = tsum[tid] - myc;
    rbase[tid] = excl;
    cnt[tid]   = excl;          // reuse as scatter cursor
    if (tid == 0) rbase[512] = n;
    __syncthreads();
    // phase A3: scatter to (seg,row)-sorted LDS position, KEEP rowlo bits
    for (int k = tid; k < n; k += 512) {
        const int2 e = recb[k];
        const int key = (((e.x & 0xFFFFF) >> 14) << 6) | ((e.x >> 20) & 63);
        const int p = atomicAdd(&cnt[key], 1);
        elist[p] = e;
    }
    __syncthreads();

    // phase B: per segment, contiguous 8-row range, 8-deep batches,
    // wave-uniform scalar switch into acc[rowlo & 7]
    const int w    = tid >> 6;
    const int lane = tid & 63;
    const unsigned* __restrict__ supl = sup16 + lane;
    const int fo = lane * 2;
    const float2 b2 = *(const float2*)&bias[fo];

    float2 acc[8];
#pragma unroll
    for (int r = 0; r < 8; ++r) acc[r] = make_float2(0.f, 0.f);

#define GDISPATCH(EX, PX, PY, VV)                                         \
    {                                                                     \
        const int rl_ = (__builtin_amdgcn_readfirstlane(EX) >> 20) & 7;   \
        switch (rl_) {                                                    \
        case 0: acc[0].x = fmaf(PX, VV, acc[0].x); acc[0].y = fmaf(PY, VV, acc[0].y); break; \
        case 1: acc[1].x = fmaf(PX, VV, acc[1].x); acc[1].y = fmaf(PY, VV, acc[1].y); break; \
        case 2: acc[2].x = fmaf(PX, VV, acc[2].x); acc[2].y = fmaf(PY, VV, acc[2].y); break; \
        case 3: acc[3].x = fmaf(PX, VV, acc[3].x); acc[3].y = fmaf(PY, VV, acc[3].y); break; \
        case 4: acc[4].x = fmaf(PX, VV, acc[4].x); acc[4].y = fmaf(PY, VV, acc[4].y); break; \
        case 5: acc[5].x = fmaf(PX, VV, acc[5].x); acc[5].y = fmaf(PY, VV, acc[5].y); break; \
        case 6: acc[6].x = fmaf(PX, VV, acc[6].x); acc[6].y = fmaf(PY, VV, acc[6].y); break; \
        default: acc[7].x = fmaf(PX, VV, acc[7].x); acc[7].y = fmaf(PY, VV, acc[7].y); break; \
        }                                                                 \
    }

#pragma unroll 1
    for (int seg = 0; seg < NSEG; ++seg) {
        const int kb = seg * 64 + (w << 3);
        int j        = __builtin_amdgcn_readfirstlane(rbase[kb]);
        const int j1 = __builtin_amdgcn_readfirstlane(rbase[kb + 8]);
#pragma unroll 1
        for (; j + 8 <= j1; j += 8) {
            int2 e[8];
#pragma unroll
            for (int q = 0; q < 8; ++q) e[q] = elist[j + q];
            unsigned u[8];
#pragma unroll
            for (int q = 0; q < 8; ++q)
                u[q] = supl[(unsigned)(e[q].x & 0xFFFFF) << 6];
#pragma unroll
            for (int q = 0; q < 8; ++q) {
                const float vv = __int_as_float(e[q].y);
                const float2 p = bfpair(u[q]);
                GDISPATCH(e[q].x, p.x, p.y, vv)
            }
        }
        for (; j < j1; ++j) {
            const int2 e = elist[j];
            const unsigned uu = supl[(unsigned)(e.x & 0xFFFFF) << 6];
            const float vv = __int_as_float(e.y);
            const float2 p = bfpair(uu);
            GDISPATCH(e.x, p.x, p.y, vv)
        }
    }
#undef GDISPATCH

    // finalize
#pragma unroll
    for (int rr = 0; rr < 8; ++rr) {
        const int row = b * 64 + (w << 3) + rr;
        if (row < M_NODES) {
            const float inv = 1.0f / norm[row];
            float2 o;
            o.x = fmaf(acc[rr].x, inv, b2.x);
            o.y = fmaf(acc[rr].y, inv, b2.y);
            *(float2*)&out[(size_t)row * D + fo] = o;
        }
    }
}

// ---------------- fallback path (fp32 support + atomic scatter) --------------
__global__ __launch_bounds__(256) void gemm32_kernel(const float* __restrict__ x,
                                                     const float* __restrict__ w,
                                                     float* __restrict__ support,
                                                     int M) {
    __shared__ float sX[32][64];
    __shared__ float sW[32][128];
    const int tid = threadIdx.x;
    const int r0  = blockIdx.x * 64;
    const int tx  = tid & 31;
    const int ty  = tid >> 5;
    float acc[8][4];
#pragma unroll
    for (int r = 0; r < 8; ++r)
#pragma unroll
        for (int c = 0; c < 4; ++c) acc[r][c] = 0.f;
    for (int c0 = 0; c0 < 128; c0 += 32) {
        {
            const int row = tid >> 3;
            const int kk  = (tid & 7) * 4;
#pragma unroll
            for (int h = 0; h < 2; ++h) {
                const int rr = row + h * 32;
                float4 v = make_float4(0.f, 0.f, 0.f, 0.f);
                if (r0 + rr < M)
                    v = *(const float4*)&x[(size_t)(r0 + rr) * D + c0 + kk];
                sX[kk + 0][rr] = v.x; sX[kk + 1][rr] = v.y;
                sX[kk + 2][rr] = v.z; sX[kk + 3][rr] = v.w;
            }
        }
#pragma unroll
        for (int i = tid; i < 1024; i += 256) {
            const int k  = i >> 5;
            const int c4 = (i & 31) * 4;
            *(float4*)&sW[k][c4] = *(const float4*)&w[(size_t)(c0 + k) * D + c4];
        }
        __syncthreads();
#pragma unroll
        for (int k = 0; k < 32; ++k) {
            const float4 wv = *(const float4*)&sW[k][tx * 4];
            const float4 xa = *(const float4*)&sX[k][ty * 8];
            const float4 xb = *(const float4*)&sX[k][ty * 8 + 4];
            const float xr[8] = {xa.x, xa.y, xa.z, xa.w, xb.x, xb.y, xb.z, xb.w};
#pragma unroll
            for (int r = 0; r < 8; ++r) {
                acc[r][0] += xr[r] * wv.x; acc[r][1] += xr[r] * wv.y;
                acc[r][2] += xr[r] * wv.z; acc[r][3] += xr[r] * wv.w;
            }
        }
        __syncthreads();
    }
#pragma unroll
    for (int r = 0; r < 8; ++r) {
        const int row = r0 + ty * 8 + r;
        if (row < M)
            *(float4*)&support[(size_t)row * D + tx * 4] =
                make_float4(acc[r][0], acc[r][1], acc[r][2], acc[r][3]);
    }
}

__global__ __launch_bounds__(256) void spmm_kernel(const float* __restrict__ support,
                                                   const int* __restrict__ rows,
                                                   const int* __restrict__ cols,
                                                   const float* __restrict__ vals,
                                                   float* __restrict__ out) {
    const long long t = (long long)blockIdx.x * 256 + threadIdx.x;
    const int e = (int)(t >> 5);
    if (e >= N_EDGES) return;
    const int f   = (int)(t & 31) * 4;
    const int src = cols[e];
    const int dst = rows[e];
    const float v = vals[e];
    const float4 s = *(const float4*)&support[(size_t)src * D + f];
    float* o = &out[(size_t)dst * D + f];
    atomicAdd(o + 0, s.x * v);
    atomicAdd(o + 1, s.y * v);
    atomicAdd(o + 2, s.z * v);
    atomicAdd(o + 3, s.w * v);
}

__global__ __launch_bounds__(256) void finalize_kernel(float* __restrict__ out,
                                                       const float* __restrict__ norm,
                                                       const float* __restrict__ bias) {
    const int t = blockIdx.x * 256 + threadIdx.x;
    const int nrow = t >> 5;
    if (nrow >= M_NODES) return;
    const int f = (t & 31) * 4;
    const float inv = 1.0f / norm[nrow];
    float4 o = *(float4*)&out[(size_t)nrow * D + f];
    const float4 b = *(const float4*)&bias[f];
    o.x = o.x * inv + b.x; o.y = o.y * inv + b.y;
    o.z = o.z * inv + b.z; o.w = o.w * inv + b.w;
    *(float4*)&out[(size_t)nrow * D + f] = o;
}

extern "C" void kernel_launch(void* const* d_in, const int* in_sizes, int n_in,
                              void* d_out, int out_size, void* d_ws, size_t ws_size,
                              hipStream_t stream) {
    const float* x    = (const float*)d_in[0];
    const float* w    = (const float*)d_in[1];
    const float* bias = (const float*)d_in[2];
    const int*   rows = (const int*)d_in[3];
    const int*   cols = (const int*)d_in[4];
    const float* vals = (const float*)d_in[5];
    const float* norm = (const float*)d_in[6];
    float* out = (float*)d_out;
    char* ws = (char*)d_ws;

    if (ws_size >= WS_NEEDED) {
        unsigned* sup16 = (unsigned*)(ws + OFF_SUP16);
        int*      bcnt  = (int*)(ws + OFF_BCNT);
        int2*     rec   = (int2*)(ws + OFF_REC);

        hipMemsetAsync(bcnt, 0, NBUCK * sizeof(int), stream);
        prep_kernel<<<PREP_BLOCKS, 512, 0, stream>>>(x, w, sup16, rows, cols, vals,
                                                     bcnt, rec, M_NODES);
        gather_kernel<<<NBUCK, 512, 0, stream>>>(sup16, bcnt, rec,
                                                 norm, bias, out);
    } else {
        // fallback: fp32 support + atomic scatter
        float* support = (float*)ws;
        gemm32_kernel<<<(M_NODES + 63) / 64, 256, 0, stream>>>(x, w, support, M_NODES);
        hipMemsetAsync(d_out, 0, (size_t)out_size * sizeof(float), stream);
        const long long spmm_threads = (long long)N_EDGES * 32;
        spmm_kernel<<<(int)((spmm_threads + 255) / 256), 256, 0, stream>>>(support, rows, cols, vals, out);
        finalize_kernel<<<(M_NODES * 32 + 255) / 256, 256, 0, stream>>>(out, norm, bias);
    }
}

// Round 11
// 312.972 us; speedup vs baseline: 1.4319x; 1.4319x over previous
//
#include <hip/hip_runtime.h>

#define M_NODES 100000
#define N_EDGES 3200000
#define D 128
#define NBUCK 1563            // ceil(100000 / 64) buckets of 64 rows (gather tiles)
#define FILL_CHUNK 12288      // edges per fill block (512 thr * 6 * 4)
#define FILL_BLOCKS 261       // ceil(3.2M / 12288)
#define GEMM_BLOCKS 1563      // ceil(100000 / 64) row tiles of 64 (MFMA)
#define PREP_BLOCKS (FILL_BLOCKS + GEMM_BLOCKS)
#define BUCK_CAP 4096         // fixed slots per bucket (mean 2048, sigma ~45)

// ---------------- workspace layout (bytes) ----------------
#define OFF_SUP16  0ull            // 100000*64 u32 (paired bf16) = 25,600,000
#define OFF_BCNT   25600000ull     // 1563 int (+pad to 8192)
#define OFF_REC    25608192ull     // 1563*4096 int2 = 51,216,384 (fixed slots)
#define WS_NEEDED  76824576ull

typedef __attribute__((ext_vector_type(8))) short short8;
typedef __attribute__((ext_vector_type(4))) float f32x4;

__device__ __forceinline__ unsigned short f2bf(float f) {
    unsigned u = __float_as_uint(f);
    u += 0x7fff + ((u >> 16) & 1);      // round-to-nearest-even
    return (unsigned short)(u >> 16);
}
__device__ __forceinline__ float bf2f(unsigned short h) {
    return __uint_as_float((unsigned)h << 16);
}
// word k of a row holds features (2k, 2k+1)
__device__ __forceinline__ float2 bfpair(unsigned u) {
    float2 r;
    r.x = __uint_as_float(u << 16);
    r.y = __uint_as_float(u & 0xffff0000u);
    return r;
}

// ---------------- fused prep: edge fill (memory-bound) + MFMA GEMM -----------
// blocks [0, FILL_BLOCKS)   : bucket-sort 12288 edges into fixed per-bucket
//                             slots rec[b*4096 ...].
// blocks [FILL_BLOCKS, end) : sup16 = bf16(x @ W) via MFMA 16x16x32_bf16 with
//                             hi/lo split (x_hi*W_hi + x_lo*W_hi + x_hi*W_lo).
__global__ __launch_bounds__(512) void prep_kernel(const float* __restrict__ x,
                                                   const float* __restrict__ w,
                                                   unsigned* __restrict__ sup16,
                                                   const int* __restrict__ rows,
                                                   const int* __restrict__ cols,
                                                   const float* __restrict__ vals,
                                                   int* __restrict__ bcnt,
                                                   int2* __restrict__ rec,
                                                   int M) {
    __shared__ __align__(16) char smem[37120];
    const int tid = threadIdx.x;

    if (blockIdx.x < FILL_BLOCKS) {
        // ---- fill path: block-batched bucket sort into fixed slots ----
        int* cnt = (int*)smem;                            // 6252 B
        int* bas = (int*)(smem + 6256);                   // 6252 B
        unsigned short* lrank = (unsigned short*)(smem + 12512); // 24576 B
        for (int i = tid; i < NBUCK; i += 512) cnt[i] = 0;
        __syncthreads();
        const long long base = (long long)blockIdx.x * FILL_CHUNK;

        // phase 1: per-edge rank within (block, bucket)
#pragma unroll
        for (int i = 0; i < 6; ++i) {
            const int li = (i * 512 + tid) * 4;
            const long long e = base + li;
            if (e < N_EDGES) {
                const int4 r = *(const int4*)&rows[e];
                lrank[li + 0] = (unsigned short)atomicAdd(&cnt[r.x >> 6], 1);
                lrank[li + 1] = (unsigned short)atomicAdd(&cnt[r.y >> 6], 1);
                lrank[li + 2] = (unsigned short)atomicAdd(&cnt[r.z >> 6], 1);
                lrank[li + 3] = (unsigned short)atomicAdd(&cnt[r.w >> 6], 1);
            }
        }
        __syncthreads();
        // phase 2: reserve a run in the bucket's fixed slot range
        for (int i = tid; i < NBUCK; i += 512)
            bas[i] = cnt[i] ? atomicAdd(&bcnt[i], cnt[i]) : 0;
        __syncthreads();
        // phase 3: scatter records (drop beyond cap; >40 sigma, never in practice)
#pragma unroll
        for (int i = 0; i < 6; ++i) {
            const int li = (i * 512 + tid) * 4;
            const long long e = base + li;
            if (e < N_EDGES) {
                const int4   r = *(const int4*)&rows[e];
                const int4   c = *(const int4*)&cols[e];
                const float4 v = *(const float4*)&vals[e];
                int p;
                p = bas[r.x >> 6] + lrank[li + 0];
                if (p < BUCK_CAP)
                    rec[(size_t)(r.x >> 6) * BUCK_CAP + p] =
                        make_int2(c.x | ((r.x & 63) << 20), __float_as_int(v.x));
                p = bas[r.y >> 6] + lrank[li + 1];
                if (p < BUCK_CAP)
                    rec[(size_t)(r.y >> 6) * BUCK_CAP + p] =
                        make_int2(c.y | ((r.y & 63) << 20), __float_as_int(v.y));
                p = bas[r.z >> 6] + lrank[li + 2];
                if (p < BUCK_CAP)
                    rec[(size_t)(r.z >> 6) * BUCK_CAP + p] =
                        make_int2(c.z | ((r.z & 63) << 20), __float_as_int(v.z));
                p = bas[r.w >> 6] + lrank[li + 3];
                if (p < BUCK_CAP)
                    rec[(size_t)(r.w >> 6) * BUCK_CAP + p] =
                        make_int2(c.w | ((r.w & 63) << 20), __float_as_int(v.w));
            }
        }
        return;
    }

    // ---- GEMM path: MFMA, 64-row tile, 8 waves -------------------------------
    // LDS (padded stride 40 bf16 = 80 B: 16B-aligned b128 frags, ~4-way banks):
    short* xh = (short*)smem;               // [64][40]  x_hi   (5120 B)
    short* xl = (short*)(smem + 5120);      // [64][40]  x_lo   (5120 B)
    short* wh = (short*)(smem + 10240);     // [128][40] W_hi^T (10240 B)
    short* wl = (short*)(smem + 20480);     // [128][40] W_lo^T (10240 B)

    const int r0   = (blockIdx.x - FILL_BLOCKS) * 64;
    const int wv   = tid >> 6;        // wave 0..7
    const int lane = tid & 63;
    const int g    = lane >> 4;       // k-group 0..3
    const int ml   = lane & 15;

    const int mt = wv & 3;            // m-tile (rows mt*16..+15)
    const int ng = (wv >> 2) * 4;     // first n-tile (cols ng*16..)

    f32x4 acc[4];
#pragma unroll
    for (int i = 0; i < 4; ++i) acc[i] = (f32x4){0.f, 0.f, 0.f, 0.f};

    for (int c0 = 0; c0 < 128; c0 += 32) {
        // stage x chunk: 64 rows x 32 k -> hi/lo bf16
        {
            const int r  = tid >> 3;           // 0..63
            const int k0 = (tid & 7) * 4;      // 0..28
            float4 v = make_float4(0.f, 0.f, 0.f, 0.f);
            if (r0 + r < M)
                v = *(const float4*)&x[(size_t)(r0 + r) * D + c0 + k0];
            unsigned short h0 = f2bf(v.x), h1 = f2bf(v.y),
                           h2 = f2bf(v.z), h3 = f2bf(v.w);
            unsigned short l0 = f2bf(v.x - bf2f(h0)), l1 = f2bf(v.y - bf2f(h1)),
                           l2 = f2bf(v.z - bf2f(h2)), l3 = f2bf(v.w - bf2f(h3));
            uint2 ph, pl;
            ph.x = (unsigned)h0 | ((unsigned)h1 << 16);
            ph.y = (unsigned)h2 | ((unsigned)h3 << 16);
            pl.x = (unsigned)l0 | ((unsigned)l1 << 16);
            pl.y = (unsigned)l2 | ((unsigned)l3 << 16);
            *(uint2*)&xh[r * 40 + k0] = ph;
            *(uint2*)&xl[r * 40 + k0] = pl;
        }
        // stage W chunk transposed: 32 k x 128 col -> hi/lo bf16 at [col][k]
        {
            const int k    = tid >> 4;         // 0..31
            const int col0 = (tid & 15) * 8;   // 0..120
            const float4 a = *(const float4*)&w[(size_t)(c0 + k) * D + col0];
            const float4 bq = *(const float4*)&w[(size_t)(c0 + k) * D + col0 + 4];
            const float vv[8] = {a.x, a.y, a.z, a.w, bq.x, bq.y, bq.z, bq.w};
#pragma unroll
            for (int j = 0; j < 8; ++j) {
                const unsigned short h = f2bf(vv[j]);
                wh[(col0 + j) * 40 + k] = (short)h;
                wl[(col0 + j) * 40 + k] = (short)f2bf(vv[j] - bf2f(h));
            }
        }
        __syncthreads();

        // MFMA: A lane(row=ml, k=g*8+j), B lane(col=ml, k=g*8+j)
        const short8 a_hi = *(const short8*)&xh[(mt * 16 + ml) * 40 + g * 8];
        const short8 a_lo = *(const short8*)&xl[(mt * 16 + ml) * 40 + g * 8];
#pragma unroll
        for (int i = 0; i < 4; ++i) {
            const int col = (ng + i) * 16 + ml;
            const short8 b_hi = *(const short8*)&wh[col * 40 + g * 8];
            const short8 b_lo = *(const short8*)&wl[col * 40 + g * 8];
            acc[i] = __builtin_amdgcn_mfma_f32_16x16x32_bf16(a_hi, b_hi, acc[i], 0, 0, 0);
            acc[i] = __builtin_amdgcn_mfma_f32_16x16x32_bf16(a_lo, b_hi, acc[i], 0, 0, 0);
            acc[i] = __builtin_amdgcn_mfma_f32_16x16x32_bf16(a_hi, b_lo, acc[i], 0, 0, 0);
        }
        __syncthreads();
    }

    // epilogue: D elem at (row = g*4+reg, col = ml) within tile; pair adjacent
    // cols via shfl_xor(1) -> one u32 word (2k,2k+1), even-col lanes store.
#pragma unroll
    for (int i = 0; i < 4; ++i) {
#pragma unroll
        for (int reg = 0; reg < 4; ++reg) {
            const float mine  = acc[i][reg];
            const float other = __shfl_xor(mine, 1);
            if (!(lane & 1)) {
                const unsigned uo = (unsigned)f2bf(mine) | ((unsigned)f2bf(other) << 16);
                const int grow = r0 + mt * 16 + g * 4 + reg;
                if (grow < M) {
                    const int word = (wv >> 2) * 32 + i * 8 + (ml >> 1);
                    sup16[(size_t)grow * 64 + word] = uo;
                }
            }
        }
    }
}

// ---------------- gather-reduce: in-LDS row sort + register-acc gather -------
// (verbatim round-6 known-good version: ~114 us, 8-deep MLP, row-serial,
//  static compile-time accumulator indexing — the only consume structure that
//  survived; per-edge dispatch indirection refuted 3x: r2/r8/r10)
__global__ __launch_bounds__(512) void gather_kernel(const unsigned* __restrict__ sup16,
                                                     const int* __restrict__ bcnt,
                                                     const int2* __restrict__ rec,
                                                     const float* __restrict__ norm,
                                                     const float* __restrict__ bias,
                                                     float* __restrict__ out) {
    __shared__ int2 elist[BUCK_CAP];              // 32 KB row-sorted edges
    __shared__ int cnt[64];
    __shared__ int rbase[65];
    const int tid = threadIdx.x;
    const int b   = blockIdx.x;

    if (tid < 64) cnt[tid] = 0;
    __syncthreads();
    const int n = min(bcnt[b], BUCK_CAP);
    const int2* __restrict__ recb = rec + (size_t)b * BUCK_CAP;

    // phase A1: count per row
    for (int k = tid; k < n; k += 512)
        atomicAdd(&cnt[(recb[k].x >> 20) & 63], 1);
    __syncthreads();
    // phase A2: serial exclusive scan of 64 counts
    if (tid == 0) {
        int run = 0;
#pragma unroll
        for (int i = 0; i < 64; ++i) {
            rbase[i] = run;
            run += cnt[i];
        }
        rbase[64] = run;
    }
    __syncthreads();
    if (tid < 64) cnt[tid] = rbase[tid];   // reuse cnt as scatter cursor
    __syncthreads();
    // phase A3: scatter to row-sorted LDS position (re-read recb, L2-hot)
    for (int k = tid; k < n; k += 512) {
        const int2 e = recb[k];
        const int p = atomicAdd(&cnt[(e.x >> 20) & 63], 1);
        elist[p] = make_int2(e.x & 0xFFFFF, e.y);
    }
    __syncthreads();

    // phase B: per-wave register-accumulator gather
    const int w    = tid >> 6;
    const int lane = tid & 63;
    const unsigned* __restrict__ supl = sup16 + lane;
    const int fo = lane * 2;
    const float2 b2 = *(const float2*)&bias[fo];

#pragma unroll 1
    for (int rr = 0; rr < 8; ++rr) {
        const int rl  = w * 8 + rr;
        const int row = b * 64 + rl;
        if (row >= M_NODES) break;                 // only last bucket, ascending
        const int j0 = rbase[rl];
        const int j1 = rbase[rl + 1];
        float2 acc = make_float2(0.f, 0.f);
        int j = j0;
        for (; j + 8 <= j1; j += 8) {
            int2 e[8];
#pragma unroll
            for (int q = 0; q < 8; ++q) e[q] = elist[j + q];
            unsigned u[8];
#pragma unroll
            for (int q = 0; q < 8; ++q) u[q] = supl[(unsigned)e[q].x << 6];
#pragma unroll
            for (int q = 0; q < 8; ++q) {
                const float v = __int_as_float(e[q].y);
                const float2 p = bfpair(u[q]);
                acc.x = fmaf(p.x, v, acc.x);
                acc.y = fmaf(p.y, v, acc.y);
            }
        }
        for (; j + 2 <= j1; j += 2) {
            const int2 e0 = elist[j];
            const int2 e1 = elist[j + 1];
            const unsigned u0 = supl[(unsigned)e0.x << 6];
            const unsigned u1 = supl[(unsigned)e1.x << 6];
            const float2 p0 = bfpair(u0);
            const float2 p1 = bfpair(u1);
            const float v0 = __int_as_float(e0.y);
            const float v1 = __int_as_float(e1.y);
            acc.x = fmaf(p0.x, v0, acc.x);
            acc.y = fmaf(p0.y, v0, acc.y);
            acc.x = fmaf(p1.x, v1, acc.x);
            acc.y = fmaf(p1.y, v1, acc.y);
        }
        for (; j < j1; ++j) {
            const int2 e = elist[j];
            const unsigned u = supl[(unsigned)e.x << 6];
            const float v = __int_as_float(e.y);
            const float2 p = bfpair(u);
            acc.x = fmaf(p.x, v, acc.x);
            acc.y = fmaf(p.y, v, acc.y);
        }
        const float inv = 1.0f / norm[row];
        float2 o;
        o.x = fmaf(acc.x, inv, b2.x);
        o.y = fmaf(acc.y, inv, b2.y);
        *(float2*)&out[(size_t)row * D + fo] = o;
    }
}

// ---------------- fallback path (fp32 support + atomic scatter) --------------
__global__ __launch_bounds__(256) void gemm32_kernel(const float* __restrict__ x,
                                                     const float* __restrict__ w,
                                                     float* __restrict__ support,
                                                     int M) {
    __shared__ float sX[32][64];
    __shared__ float sW[32][128];
    const int tid = threadIdx.x;
    const int r0  = blockIdx.x * 64;
    const int tx  = tid & 31;
    const int ty  = tid >> 5;
    float acc[8][4];
#pragma unroll
    for (int r = 0; r < 8; ++r)
#pragma unroll
        for (int c = 0; c < 4; ++c) acc[r][c] = 0.f;
    for (int c0 = 0; c0 < 128; c0 += 32) {
        {
            const int row = tid >> 3;
            const int kk  = (tid & 7) * 4;
#pragma unroll
            for (int h = 0; h < 2; ++h) {
                const int rr = row + h * 32;
                float4 v = make_float4(0.f, 0.f, 0.f, 0.f);
                if (r0 + rr < M)
                    v = *(const float4*)&x[(size_t)(r0 + rr) * D + c0 + kk];
                sX[kk + 0][rr] = v.x; sX[kk + 1][rr] = v.y;
                sX[kk + 2][rr] = v.z; sX[kk + 3][rr] = v.w;
            }
        }
#pragma unroll
        for (int i = tid; i < 1024; i += 256) {
            const int k  = i >> 5;
            const int c4 = (i & 31) * 4;
            *(float4*)&sW[k][c4] = *(const float4*)&w[(size_t)(c0 + k) * D + c4];
        }
        __syncthreads();
#pragma unroll
        for (int k = 0; k < 32; ++k) {
            const float4 wv = *(const float4*)&sW[k][tx * 4];
            const float4 xa = *(const float4*)&sX[k][ty * 8];
            const float4 xb = *(const float4*)&sX[k][ty * 8 + 4];
            const float xr[8] = {xa.x, xa.y, xa.z, xa.w, xb.x, xb.y, xb.z, xb.w};
#pragma unroll
            for (int r = 0; r < 8; ++r) {
                acc[r][0] += xr[r] * wv.x; acc[r][1] += xr[r] * wv.y;
                acc[r][2] += xr[r] * wv.z; acc[r][3] += xr[r] * wv.w;
            }
        }
        __syncthreads();
    }
#pragma unroll
    for (int r = 0; r < 8; ++r) {
        const int row = r0 + ty * 8 + r;
        if (row < M)
            *(float4*)&support[(size_t)row * D + tx * 4] =
                make_float4(acc[r][0], acc[r][1], acc[r][2], acc[r][3]);
    }
}

__global__ __launch_bounds__(256) void spmm_kernel(const float* __restrict__ support,
                                                   const int* __restrict__ rows,
                                                   const int* __restrict__ cols,
                                                   const float* __restrict__ vals,
                                                   float* __restrict__ out) {
    const long long t = (long long)blockIdx.x * 256 + threadIdx.x;
    const int e = (int)(t >> 5);
    if (e >= N_EDGES) return;
    const int f   = (int)(t & 31) * 4;
    const int src = cols[e];
    const int dst = rows[e];
    const float v = vals[e];
    const float4 s = *(const float4*)&support[(size_t)src * D + f];
    float* o = &out[(size_t)dst * D + f];
    atomicAdd(o + 0, s.x * v);
    atomicAdd(o + 1, s.y * v);
    atomicAdd(o + 2, s.z * v);
    atomicAdd(o + 3, s.w * v);
}

__global__ __launch_bounds__(256) void finalize_kernel(float* __restrict__ out,
                                                       const float* __restrict__ norm,
                                                       const float* __restrict__ bias) {
    const int t = blockIdx.x * 256 + threadIdx.x;
    const int nrow = t >> 5;
    if (nrow >= M_NODES) return;
    const int f = (t & 31) * 4;
    const float inv = 1.0f / norm[nrow];
    float4 o = *(float4*)&out[(size_t)nrow * D + f];
    const float4 b = *(const float4*)&bias[f];
    o.x = o.x * inv + b.x; o.y = o.y * inv + b.y;
    o.z = o.z * inv + b.z; o.w = o.w * inv + b.w;
    *(float4*)&out[(size_t)nrow * D + f] = o;
}

extern "C" void kernel_launch(void* const* d_in, const int* in_sizes, int n_in,
                              void* d_out, int out_size, void* d_ws, size_t ws_size,
                              hipStream_t stream) {
    const float* x    = (const float*)d_in[0];
    const float* w    = (const float*)d_in[1];
    const float* bias = (const float*)d_in[2];
    const int*   rows = (const int*)d_in[3];
    const int*   cols = (const int*)d_in[4];
    const float* vals = (const float*)d_in[5];
    const float* norm = (const float*)d_in[6];
    float* out = (float*)d_out;
    char* ws = (char*)d_ws;

    if (ws_size >= WS_NEEDED) {
        unsigned* sup16 = (unsigned*)(ws + OFF_SUP16);
        int*      bcnt  = (int*)(ws + OFF_BCNT);
        int2*     rec   = (int2*)(ws + OFF_REC);

        hipMemsetAsync(bcnt, 0, NBUCK * sizeof(int), stream);
        prep_kernel<<<PREP_BLOCKS, 512, 0, stream>>>(x, w, sup16, rows, cols, vals,
                                                     bcnt, rec, M_NODES);
        gather_kernel<<<NBUCK, 512, 0, stream>>>(sup16, bcnt, rec,
                                                 norm, bias, out);
    } else {
        // fallback: fp32 support + atomic scatter
        float* support = (float*)ws;
        gemm32_kernel<<<(M_NODES + 63) / 64, 256, 0, stream>>>(x, w, support, M_NODES);
        hipMemsetAsync(d_out, 0, (size_t)out_size * sizeof(float), stream);
        const long long spmm_threads = (long long)N_EDGES * 32;
        spmm_kernel<<<(int)((spmm_threads + 255) / 256), 256, 0, stream>>>(support, rows, cols, vals, out);
        finalize_kernel<<<(M_NODES * 32 + 255) / 256, 256, 0, stream>>>(out, norm, bias);
    }
}